// Round 7
// baseline (211.662 us; speedup 1.0000x reference)
//
#include <hip/hip_runtime.h>
#include <math.h>

#define IN_DIM 256
#define H_DIM  128
#define C_DIM  16
#define BK_SHIFT 8
#define BK_CAP   6144
#define CHUNK    4096

typedef __attribute__((ext_vector_type(8))) short bf16x8;
typedef __attribute__((ext_vector_type(4))) float f32x4;

__device__ __forceinline__ ushort f2bf(float f) {
    uint u = __float_as_uint(f);
    u += 0x7fffu + ((u >> 16) & 1u);   // round to nearest even
    return (ushort)(u >> 16);
}
__device__ __forceinline__ float bflo(uint v) { return __uint_as_float(v << 16); }
__device__ __forceinline__ float bfhi(uint v) { return __uint_as_float(v & 0xffff0000u); }
__device__ __forceinline__ uint pk2(float a, float b) {
    return (uint)f2bf(a) | ((uint)f2bf(b) << 16);
}

__global__ void k_zero(int* __restrict__ p, int n) {
    int i = blockIdx.x * blockDim.x + threadIdx.x;
    if (i < n) p[i] = 0;
}

// ---------------- Pass 1: partition edges into 256-node buckets ----------------
__global__ __launch_bounds__(256) void k_part(const int* __restrict__ esrc, const int* __restrict__ edst, int E,
                                              int* __restrict__ bcnt, int2* __restrict__ part) {
    __shared__ int sh_cnt[512];
    __shared__ int sh_base[512];
    __shared__ int sh_gbase[512];
    __shared__ int sh_scan[256];
    __shared__ int2 sh_rec[CHUNK];
    int t = threadIdx.x;
    int c0 = blockIdx.x * CHUNK;
    int cnt = min(CHUNK, E - c0);
    sh_cnt[t] = 0; sh_cnt[t + 256] = 0;
    __syncthreads();
    int srcv[16], dstv[16], lrank[16];
#pragma unroll
    for (int j = 0; j < 16; j++) {
        int li = j * 256 + t;
        if (li < cnt) {
            srcv[j] = esrc[c0 + li]; dstv[j] = edst[c0 + li];
            lrank[j] = atomicAdd(&sh_cnt[dstv[j] >> BK_SHIFT], 1);
        }
    }
    __syncthreads();
    int pairsum = sh_cnt[2 * t] + sh_cnt[2 * t + 1];
    sh_scan[t] = pairsum;
    __syncthreads();
    for (int off = 1; off < 256; off <<= 1) {
        int x = 0;
        if (t >= off) x = sh_scan[t - off];
        __syncthreads();
        if (t >= off) sh_scan[t] += x;
        __syncthreads();
    }
    int excl = sh_scan[t] - pairsum;
    sh_base[2 * t] = excl;
    sh_base[2 * t + 1] = excl + sh_cnt[2 * t];
    __syncthreads();
    for (int b = t; b < 512; b += 256) {
        int c = sh_cnt[b];
        if (c > 0) sh_gbase[b] = atomicAdd(&bcnt[b], c);
    }
#pragma unroll
    for (int j = 0; j < 16; j++) {
        int li = j * 256 + t;
        if (li < cnt) {
            int b = dstv[j] >> BK_SHIFT;
            sh_rec[sh_base[b] + lrank[j]] = make_int2(srcv[j], dstv[j]);
        }
    }
    __syncthreads();
    for (int idx = t; idx < cnt; idx += 256) {
        int2 r = sh_rec[idx];
        int b = r.y >> BK_SHIFT;
        int pos = sh_gbase[b] + (idx - sh_base[b]);
        if (pos < BK_CAP) part[(size_t)b * BK_CAP + pos] = r;
    }
}

// ---------------- Pass 2a: per-bucket degree histogram -> deg, dis ----------------
__global__ __launch_bounds__(256) void k_bdeg(const int* __restrict__ bcnt, const int2* __restrict__ part,
                                              int* __restrict__ deg, float* __restrict__ dis, int N) {
    __shared__ int hist[256];
    int b = blockIdx.x, t = threadIdx.x;
    hist[t] = 0;
    __syncthreads();
    int cnt = bcnt[b];
    const int2* bp = &part[(size_t)b * BK_CAP];
    for (int idx = t; idx < cnt; idx += 256)
        atomicAdd(&hist[bp[idx].y & 255], 1);
    __syncthreads();
    int node = b * 256 + t;
    if (node < N) {
        deg[node] = hist[t];
        dis[node] = rsqrtf((float)(hist[t] + 1));  // +1 self loop
    }
}

// ---------------- offsets scan ----------------
__global__ void k_scanA(const int* __restrict__ deg, int* __restrict__ bsums, int N) {
    __shared__ int sh[256];
    int b = blockIdx.x, t = threadIdx.x;
    int i0 = b * 2048 + t * 8;
    int s = 0;
#pragma unroll
    for (int j = 0; j < 8; j++) { int i = i0 + j; s += (i < N) ? deg[i] : 0; }
    sh[t] = s; __syncthreads();
    for (int off = 128; off > 0; off >>= 1) {
        if (t < off) sh[t] += sh[t + off];
        __syncthreads();
    }
    if (t == 0) bsums[b] = sh[0];
}

__global__ void k_scanB(int* __restrict__ bsums, int nb, int* __restrict__ offsets, int N) {
    if (threadIdx.x == 0 && blockIdx.x == 0) {
        int run = 0;
        for (int b = 0; b < nb; b++) { int v = bsums[b]; bsums[b] = run; run += v; }
        offsets[N] = run;
    }
}

__global__ void k_scanC(const int* __restrict__ deg, const int* __restrict__ bsums,
                        int* __restrict__ offsets, int N) {
    __shared__ int sh[256];
    int b = blockIdx.x, t = threadIdx.x;
    int base = bsums[b];
    int i0 = b * 2048 + t * 8;
    int v[8], loc[8]; int s = 0;
#pragma unroll
    for (int j = 0; j < 8; j++) { int i = i0 + j; v[j] = (i < N) ? deg[i] : 0; loc[j] = s; s += v[j]; }
    sh[t] = s; __syncthreads();
    for (int off = 1; off < 256; off <<= 1) {
        int x = 0;
        if (t >= off) x = sh[t - off];
        __syncthreads();
        if (t >= off) sh[t] += x;
        __syncthreads();
    }
    int tb = base + ((t > 0) ? sh[t - 1] : 0);
#pragma unroll
    for (int j = 0; j < 8; j++) {
        int i = i0 + j;
        if (i < N) offsets[i] = tb + loc[j];
    }
}

// ---------------- Pass 2b: per-bucket counting sort -> final CSR ----------------
__global__ __launch_bounds__(256) void k_bsort(const int* __restrict__ bcnt, const int2* __restrict__ part,
                                               const float* __restrict__ dis, const int* __restrict__ offsets,
                                               int2* __restrict__ csr) {
    __shared__ int hist[256];
    __shared__ int run[256];
    __shared__ int2 srt[BK_CAP];
    int b = blockIdx.x, t = threadIdx.x;
    hist[t] = 0;
    __syncthreads();
    int cnt = min(bcnt[b], BK_CAP);
    const int2* bp = &part[(size_t)b * BK_CAP];
    for (int idx = t; idx < cnt; idx += 256)
        atomicAdd(&hist[bp[idx].y & 255], 1);
    __syncthreads();
    int v = hist[t];
    run[t] = v;
    __syncthreads();
    for (int off = 1; off < 256; off <<= 1) {
        int x = 0;
        if (t >= off) x = run[t - off];
        __syncthreads();
        if (t >= off) run[t] += x;
        __syncthreads();
    }
    int start = run[t] - v;
    __syncthreads();
    run[t] = start;
    __syncthreads();
    for (int idx = t; idx < cnt; idx += 256) {
        int2 r = bp[idx];
        int n = r.y & 255;
        int lpos = atomicAdd(&run[n], 1);
        float w = dis[r.x];
        srt[lpos] = make_int2(r.x, __float_as_int(w));
    }
    __syncthreads();
    int segbase = offsets[b * 256];
    for (int idx = t; idx < cnt; idx += 256)
        csr[segbase + idx] = srt[idx];
}

// ---------------- W1 cast+transpose ----------------
__global__ void k_w1cast(const float* __restrict__ W1, ushort* __restrict__ W1T) {
    int n = blockIdx.x, k = threadIdx.x;
    W1T[n * 256 + k] = f2bf(W1[k * 128 + n]);
}

// ---------------- GEMM1 (MFMA bf16) ----------------
__global__ __launch_bounds__(256) void k_gemm1(const float* __restrict__ x,
                                               const ushort* __restrict__ W1T,
                                               ushort* __restrict__ h1, int N) {
    __shared__ ushort Al[128 * 64];
    __shared__ ushort Bl[128 * 64];
    int tid = threadIdx.x;
    int lane = tid & 63, wid = tid >> 6;
    int wr = wid >> 1, wc = wid & 1;
    int r0 = blockIdx.x * 128;
    int row16 = lane & 15, kgrp = lane >> 4;

    f32x4 acc[4][4];
#pragma unroll
    for (int i = 0; i < 4; i++)
#pragma unroll
        for (int j = 0; j < 4; j++) acc[i][j] = (f32x4){0.f, 0.f, 0.f, 0.f};

    int srow = tid >> 1, shalf = tid & 1;

    for (int k0 = 0; k0 < 256; k0 += 64) {
        {
            int gr = r0 + srow;
            float4 f[8];
            if (gr < N) {
                const float* xp = &x[(size_t)gr * 256 + k0 + shalf * 32];
#pragma unroll
                for (int j = 0; j < 8; j++) f[j] = *(const float4*)&xp[j * 4];
            } else {
#pragma unroll
                for (int j = 0; j < 8; j++) f[j] = make_float4(0.f, 0.f, 0.f, 0.f);
            }
#pragma unroll
            for (int j = 0; j < 4; j++) {
                uint4 w;
                w.x = pk2(f[2 * j].x, f[2 * j].y);
                w.y = pk2(f[2 * j].z, f[2 * j].w);
                w.z = pk2(f[2 * j + 1].x, f[2 * j + 1].y);
                w.w = pk2(f[2 * j + 1].z, f[2 * j + 1].w);
                int idx = (srow * 64 + shalf * 32 + j * 8) ^ ((srow & 7) << 3);
                *(uint4*)&Al[idx] = w;
            }
        }
        {
            const ushort* wp = &W1T[srow * 256 + k0 + shalf * 32];
#pragma unroll
            for (int j = 0; j < 4; j++) {
                uint4 w = *(const uint4*)&wp[j * 8];
                int idx = (srow * 64 + shalf * 32 + j * 8) ^ ((srow & 7) << 3);
                *(uint4*)&Bl[idx] = w;
            }
        }
        __syncthreads();
#pragma unroll
        for (int kk = 0; kk < 2; kk++) {
            bf16x8 a[4], b[4];
#pragma unroll
            for (int mi = 0; mi < 4; mi++) {
                int r = wr * 64 + mi * 16 + row16;
                a[mi] = *(const bf16x8*)&Al[(r * 64 + kk * 32 + kgrp * 8) ^ ((r & 7) << 3)];
            }
#pragma unroll
            for (int ni = 0; ni < 4; ni++) {
                int c = wc * 64 + ni * 16 + row16;
                b[ni] = *(const bf16x8*)&Bl[(c * 64 + kk * 32 + kgrp * 8) ^ ((c & 7) << 3)];
            }
#pragma unroll
            for (int mi = 0; mi < 4; mi++)
#pragma unroll
                for (int ni = 0; ni < 4; ni++)
                    acc[mi][ni] = __builtin_amdgcn_mfma_f32_16x16x32_bf16(
                        a[mi], b[ni], acc[mi][ni], 0, 0, 0);
        }
        __syncthreads();
    }
#pragma unroll
    for (int mi = 0; mi < 4; mi++) {
        int rbase = r0 + wr * 64 + mi * 16 + kgrp * 4;
#pragma unroll
        for (int ni = 0; ni < 4; ni++) {
            int col = wc * 64 + ni * 16 + row16;
#pragma unroll
            for (int r = 0; r < 4; r++) {
                int gr = rbase + r;
                if (gr < N) h1[(size_t)gr * 128 + col] = f2bf(acc[mi][ni][r]);
            }
        }
    }
}

// ---------------- Fused agg1 + bias + ReLU + GEMM2 (quarter-wave uint4 gathers) ----------------
// 4x16-lane quarters; one VMEM instr gathers 4 edges (16B/lane); combine via shfl_xor.
__global__ __launch_bounds__(256) void k_agg1(const ushort* __restrict__ h1,
                                              const float* __restrict__ dis,
                                              const int* __restrict__ off,
                                              const int2* __restrict__ csr,
                                              const float* __restrict__ b1,
                                              const float* __restrict__ W2,
                                              ushort* __restrict__ h2, int N) {
    __shared__ float sh[4][128];
    int wave = threadIdx.x >> 6;
    int lane = threadIdx.x & 63;
    int node = blockIdx.x * 4 + wave;
    if (node >= N) return;

    int qh  = lane >> 4;     // quarter 0..3
    int c16 = lane & 15;     // uint4 column in row (8 bf16 features)
    float w2r[32];
#pragma unroll
    for (int j = 0; j < 32; j++) w2r[j] = W2[(qh * 32 + j) * 16 + c16];

    float dd = dis[node];
    const uint4* hp4 = (const uint4*)h1;
    float acc[8];
#pragma unroll
    for (int i = 0; i < 8; i++) acc[i] = 0.f;
    if (qh == 0) {  // self loop
        uint4 a = hp4[(size_t)node * 16 + c16];
        acc[0] = bflo(a.x) * dd; acc[1] = bfhi(a.x) * dd;
        acc[2] = bflo(a.y) * dd; acc[3] = bfhi(a.y) * dd;
        acc[4] = bflo(a.z) * dd; acc[5] = bfhi(a.z) * dd;
        acc[6] = bflo(a.w) * dd; acc[7] = bfhi(a.w) * dd;
    }

    int p0 = off[node], p1 = off[node + 1];
    for (int pb = p0; pb < p1; pb += 64) {
        int cnt = min(64, p1 - pb);
        int s = 0; float w = 0.f;
        if (lane < cnt) { int2 e = csr[pb + lane]; s = e.x; w = __int_as_float(e.y); }
        for (int j = 0; j < cnt; j += 16) {
            uint4 v[4]; float ww[4];
#pragma unroll
            for (int u = 0; u < 4; u++) {
                int idx = j + 4 * u + qh;    // <= 63; lanes beyond cnt carry s=0,w=0
                int ss = __shfl(s, idx);
                ww[u] = __shfl(w, idx);
                v[u] = hp4[(size_t)ss * 16 + c16];
            }
#pragma unroll
            for (int u = 0; u < 4; u++) {
                acc[0] += bflo(v[u].x) * ww[u]; acc[1] += bfhi(v[u].x) * ww[u];
                acc[2] += bflo(v[u].y) * ww[u]; acc[3] += bfhi(v[u].y) * ww[u];
                acc[4] += bflo(v[u].z) * ww[u]; acc[5] += bfhi(v[u].z) * ww[u];
                acc[6] += bflo(v[u].w) * ww[u]; acc[7] += bfhi(v[u].w) * ww[u];
            }
        }
    }
    // combine the 4 quarters
#pragma unroll
    for (int i = 0; i < 8; i++) {
        acc[i] += __shfl_xor(acc[i], 16);
        acc[i] += __shfl_xor(acc[i], 32);
    }
    // bias + relu, write features to wave-local LDS (quarter 0 holds full sums too)
    if (qh == 0) {
        float4 b0 = *(const float4*)&b1[c16 * 8];
        float4 b4 = *(const float4*)&b1[c16 * 8 + 4];
        sh[wave][c16 * 8 + 0] = fmaxf(acc[0] * dd + b0.x, 0.f);
        sh[wave][c16 * 8 + 1] = fmaxf(acc[1] * dd + b0.y, 0.f);
        sh[wave][c16 * 8 + 2] = fmaxf(acc[2] * dd + b0.z, 0.f);
        sh[wave][c16 * 8 + 3] = fmaxf(acc[3] * dd + b0.w, 0.f);
        sh[wave][c16 * 8 + 4] = fmaxf(acc[4] * dd + b4.x, 0.f);
        sh[wave][c16 * 8 + 5] = fmaxf(acc[5] * dd + b4.y, 0.f);
        sh[wave][c16 * 8 + 6] = fmaxf(acc[6] * dd + b4.z, 0.f);
        sh[wave][c16 * 8 + 7] = fmaxf(acc[7] * dd + b4.w, 0.f);
    }
    // wave-synchronous LDS RAW (same wave, in-order DS pipe)
    float cs = 0.f;
#pragma unroll
    for (int j = 0; j < 32; j++) cs += sh[wave][qh * 32 + j] * w2r[j];
    cs += __shfl_xor(cs, 16);
    cs += __shfl_xor(cs, 32);
    if (lane < 16) h2[(size_t)node * 16 + lane] = f2bf(cs);
}

// ---------------- Aggregation layer 2 + b2 + log_softmax ----------------
__global__ __launch_bounds__(256) void k_final(const ushort* __restrict__ h2,
                                               const float* __restrict__ b2,
                                               const float* __restrict__ dis,
                                               const int* __restrict__ off,
                                               const int2* __restrict__ csr,
                                               float* __restrict__ out, int N) {
    int g = threadIdx.x >> 2;
    int q = threadIdx.x & 3;
    int node = blockIdx.x * 64 + g;
    if (node >= N) return;
    float dd = dis[node];
    uint2 v0 = *(const uint2*)&h2[(size_t)node * 16 + q * 4];
    float a0 = bflo(v0.x) * dd, a1 = bfhi(v0.x) * dd;
    float a2 = bflo(v0.y) * dd, a3 = bfhi(v0.y) * dd;
    int p0 = off[node], p1 = off[node + 1];
    for (int pb = p0; pb < p1; pb += 4) {
        int rem4 = p1 - pb;
        int cnt = rem4 < 4 ? rem4 : 4;
        int s = 0; float w = 0.f;
        if (q < cnt) { int2 e = csr[pb + q]; s = e.x; w = __int_as_float(e.y); }
        uint2 vv[4]; float ww[4];
#pragma unroll
        for (int u = 0; u < 4; u++) {
            int ss = __shfl(s, u, 4);
            float t = __shfl(w, u, 4);
            ww[u] = (u < cnt) ? t : 0.f;
            if (u < cnt) vv[u] = *(const uint2*)&h2[(size_t)ss * 16 + q * 4];
            else         vv[u] = make_uint2(0u, 0u);
        }
#pragma unroll
        for (int u = 0; u < 4; u++) {
            a0 += bflo(vv[u].x) * ww[u]; a1 += bfhi(vv[u].x) * ww[u];
            a2 += bflo(vv[u].y) * ww[u]; a3 += bfhi(vv[u].y) * ww[u];
        }
    }
    a0 = a0 * dd + b2[q * 4 + 0];
    a1 = a1 * dd + b2[q * 4 + 1];
    a2 = a2 * dd + b2[q * 4 + 2];
    a3 = a3 * dd + b2[q * 4 + 3];
    float m = fmaxf(fmaxf(a0, a1), fmaxf(a2, a3));
    m = fmaxf(m, __shfl_xor(m, 1, 4));
    m = fmaxf(m, __shfl_xor(m, 2, 4));
    float s4 = expf(a0 - m) + expf(a1 - m) + expf(a2 - m) + expf(a3 - m);
    s4 += __shfl_xor(s4, 1, 4);
    s4 += __shfl_xor(s4, 2, 4);
    float l = m + logf(s4);
    f32x4 o = {a0 - l, a1 - l, a2 - l, a3 - l};
    *(f32x4*)&out[(size_t)node * 16 + q * 4] = o;
}

extern "C" void kernel_launch(void* const* d_in, const int* in_sizes, int n_in,
                              void* d_out, int out_size, void* d_ws, size_t ws_size,
                              hipStream_t stream) {
    const float* x    = (const float*)d_in[0];
    const int*   eidx = (const int*)d_in[1];
    const float* W1   = (const float*)d_in[2];
    const float* b1   = (const float*)d_in[3];
    const float* W2   = (const float*)d_in[4];
    const float* b2   = (const float*)d_in[5];
    float* out = (float*)d_out;

    int N = in_sizes[0] / IN_DIM;
    int E = in_sizes[1] / 2;
    const int* esrc = eidx;
    const int* edst = eidx + E;

    char* ws = (char*)d_ws;
    size_t wo = 0;
    auto alloc = [&](size_t bytes) -> void* {
        void* p = ws + wo;
        wo = (wo + bytes + 255) & ~(size_t)255;
        return p;
    };
    int NB = (N + 255) >> 8;   // 256-node buckets

    int*    deg     = (int*)alloc((size_t)N * 4);
    float*  dis     = (float*)alloc((size_t)N * 4);
    int*    offsets = (int*)alloc((size_t)(N + 1) * 4);
    int*    bsums   = (int*)alloc(256 * 4);
    int*    bcnt    = (int*)alloc(512 * 4);
    int2*   part    = (int2*)alloc((size_t)NB * BK_CAP * 8);
    int2*   csr     = (int2*)alloc((size_t)E * 8);
    ushort* W1T     = (ushort*)alloc((size_t)IN_DIM * H_DIM * 2);
    ushort* h1      = (ushort*)alloc((size_t)N * H_DIM * 2);
    ushort* h2      = (ushort*)alloc((size_t)N * C_DIM * 2);

    int nb_scan = (N + 2047) / 2048;

    k_zero  <<<2, 256, 0, stream>>>(bcnt, 512);
    k_part  <<<(E + CHUNK - 1) / CHUNK, 256, 0, stream>>>(esrc, edst, E, bcnt, part);
    k_bdeg  <<<NB, 256, 0, stream>>>(bcnt, part, deg, dis, N);
    k_scanA <<<nb_scan, 256, 0, stream>>>(deg, bsums, N);
    k_scanB <<<1, 64, 0, stream>>>(bsums, nb_scan, offsets, N);
    k_scanC <<<nb_scan, 256, 0, stream>>>(deg, bsums, offsets, N);
    k_bsort <<<NB, 256, 0, stream>>>(bcnt, part, dis, offsets, csr);
    k_w1cast<<<H_DIM, IN_DIM, 0, stream>>>(W1, W1T);

    k_gemm1 <<<(N + 127) / 128, 256, 0, stream>>>(x, W1T, h1, N);
    k_agg1  <<<(N + 3) / 4, 256, 0, stream>>>(h1, dis, offsets, csr, b1, W2, h2, N);
    k_final <<<(N + 63) / 64, 256, 0, stream>>>(h2, b2, dis, offsets, csr, out, N);
}

// Round 8
// 175.386 us; speedup vs baseline: 1.2068x; 1.2068x over previous
//
#include <hip/hip_runtime.h>
#include <math.h>

#define IN_DIM 256
#define H_DIM  128
#define C_DIM  16
#define BK_SHIFT 8
#define BK_CAP   6144
#define CHUNK    4096

typedef __attribute__((ext_vector_type(8))) short bf16x8;
typedef __attribute__((ext_vector_type(4))) float f32x4;

__device__ __forceinline__ ushort f2bf(float f) {
    uint u = __float_as_uint(f);
    u += 0x7fffu + ((u >> 16) & 1u);   // round to nearest even
    return (ushort)(u >> 16);
}
__device__ __forceinline__ float bflo(uint v) { return __uint_as_float(v << 16); }
__device__ __forceinline__ float bfhi(uint v) { return __uint_as_float(v & 0xffff0000u); }
__device__ __forceinline__ uint pk2(float a, float b) {
    return (uint)f2bf(a) | ((uint)f2bf(b) << 16);
}

__global__ void k_zero(int* __restrict__ p, int n) {
    int i = blockIdx.x * blockDim.x + threadIdx.x;
    if (i < n) p[i] = 0;
}

// ---------------- Pass 1: partition edges into 256-node buckets ----------------
__global__ __launch_bounds__(256) void k_part(const int* __restrict__ esrc, const int* __restrict__ edst, int E,
                                              int* __restrict__ bcnt, int2* __restrict__ part) {
    __shared__ int sh_cnt[512];
    __shared__ int sh_base[512];
    __shared__ int sh_gbase[512];
    __shared__ int sh_scan[256];
    __shared__ int2 sh_rec[CHUNK];
    int t = threadIdx.x;
    int c0 = blockIdx.x * CHUNK;
    int cnt = min(CHUNK, E - c0);
    sh_cnt[t] = 0; sh_cnt[t + 256] = 0;
    __syncthreads();
    int srcv[16], dstv[16], lrank[16];
#pragma unroll
    for (int j = 0; j < 16; j++) {
        int li = j * 256 + t;
        if (li < cnt) {
            srcv[j] = esrc[c0 + li]; dstv[j] = edst[c0 + li];
            lrank[j] = atomicAdd(&sh_cnt[dstv[j] >> BK_SHIFT], 1);
        }
    }
    __syncthreads();
    int pairsum = sh_cnt[2 * t] + sh_cnt[2 * t + 1];
    sh_scan[t] = pairsum;
    __syncthreads();
    for (int off = 1; off < 256; off <<= 1) {
        int x = 0;
        if (t >= off) x = sh_scan[t - off];
        __syncthreads();
        if (t >= off) sh_scan[t] += x;
        __syncthreads();
    }
    int excl = sh_scan[t] - pairsum;
    sh_base[2 * t] = excl;
    sh_base[2 * t + 1] = excl + sh_cnt[2 * t];
    __syncthreads();
    for (int b = t; b < 512; b += 256) {
        int c = sh_cnt[b];
        if (c > 0) sh_gbase[b] = atomicAdd(&bcnt[b], c);
    }
#pragma unroll
    for (int j = 0; j < 16; j++) {
        int li = j * 256 + t;
        if (li < cnt) {
            int b = dstv[j] >> BK_SHIFT;
            sh_rec[sh_base[b] + lrank[j]] = make_int2(srcv[j], dstv[j]);
        }
    }
    __syncthreads();
    for (int idx = t; idx < cnt; idx += 256) {
        int2 r = sh_rec[idx];
        int b = r.y >> BK_SHIFT;
        int pos = sh_gbase[b] + (idx - sh_base[b]);
        if (pos < BK_CAP) part[(size_t)b * BK_CAP + pos] = r;
    }
}

// ---------------- bucket-base scan: bkbase = exclusive_scan(bcnt[0..511]); offsets[N] = E ----------------
__global__ __launch_bounds__(256) void k_bscan(const int* __restrict__ bcnt, int* __restrict__ bkbase,
                                               int* __restrict__ offsets, int N) {
    __shared__ int sh_scan[256];
    int t = threadIdx.x;
    int a0 = bcnt[2 * t], a1 = bcnt[2 * t + 1];
    int pairsum = a0 + a1;
    sh_scan[t] = pairsum;
    __syncthreads();
    for (int off = 1; off < 256; off <<= 1) {
        int x = 0;
        if (t >= off) x = sh_scan[t - off];
        __syncthreads();
        if (t >= off) sh_scan[t] += x;
        __syncthreads();
    }
    int excl = sh_scan[t] - pairsum;
    bkbase[2 * t] = excl;
    bkbase[2 * t + 1] = excl + a0;
    if (t == 255) offsets[N] = sh_scan[255];
}

// ---------------- Pass 2: per-bucket counting sort -> csr(src-only), dis, offsets ----------------
__global__ __launch_bounds__(256) void k_bsort(const int* __restrict__ bcnt, const int* __restrict__ bkbase,
                                               const int2* __restrict__ part,
                                               float* __restrict__ dis, int* __restrict__ offsets,
                                               int* __restrict__ csr, int N) {
    __shared__ int hist[256];
    __shared__ int run[256];
    __shared__ int srt[BK_CAP];
    int b = blockIdx.x, t = threadIdx.x;
    hist[t] = 0;
    __syncthreads();
    int cnt = min(bcnt[b], BK_CAP);
    const int2* bp = &part[(size_t)b * BK_CAP];
    for (int idx = t; idx < cnt; idx += 256)
        atomicAdd(&hist[bp[idx].y & 255], 1);
    __syncthreads();
    int v = hist[t];
    run[t] = v;
    __syncthreads();
    for (int off = 1; off < 256; off <<= 1) {
        int x = 0;
        if (t >= off) x = run[t - off];
        __syncthreads();
        if (t >= off) run[t] += x;
        __syncthreads();
    }
    int start = run[t] - v;
    int base = bkbase[b];
    int node = b * 256 + t;
    if (node < N) {
        dis[node] = rsqrtf((float)(v + 1));   // +1 self loop
        offsets[node] = base + start;
    }
    __syncthreads();
    run[t] = start;
    __syncthreads();
    for (int idx = t; idx < cnt; idx += 256) {
        int2 r = bp[idx];
        int lpos = atomicAdd(&run[r.y & 255], 1);
        srt[lpos] = r.x;
    }
    __syncthreads();
    for (int idx = t; idx < cnt; idx += 256)
        csr[base + idx] = srt[idx];
}

// ---------------- W1 cast+transpose ----------------
__global__ void k_w1cast(const float* __restrict__ W1, ushort* __restrict__ W1T) {
    int n = blockIdx.x, k = threadIdx.x;
    W1T[n * 256 + k] = f2bf(W1[k * 128 + n]);
}

// ---------------- GEMM1 (MFMA bf16) ----------------
__global__ __launch_bounds__(256) void k_gemm1(const float* __restrict__ x,
                                               const ushort* __restrict__ W1T,
                                               ushort* __restrict__ h1, int N) {
    __shared__ ushort Al[128 * 64];
    __shared__ ushort Bl[128 * 64];
    int tid = threadIdx.x;
    int lane = tid & 63, wid = tid >> 6;
    int wr = wid >> 1, wc = wid & 1;
    int r0 = blockIdx.x * 128;
    int row16 = lane & 15, kgrp = lane >> 4;

    f32x4 acc[4][4];
#pragma unroll
    for (int i = 0; i < 4; i++)
#pragma unroll
        for (int j = 0; j < 4; j++) acc[i][j] = (f32x4){0.f, 0.f, 0.f, 0.f};

    int srow = tid >> 1, shalf = tid & 1;

    for (int k0 = 0; k0 < 256; k0 += 64) {
        {
            int gr = r0 + srow;
            float4 f[8];
            if (gr < N) {
                const float* xp = &x[(size_t)gr * 256 + k0 + shalf * 32];
#pragma unroll
                for (int j = 0; j < 8; j++) f[j] = *(const float4*)&xp[j * 4];
            } else {
#pragma unroll
                for (int j = 0; j < 8; j++) f[j] = make_float4(0.f, 0.f, 0.f, 0.f);
            }
#pragma unroll
            for (int j = 0; j < 4; j++) {
                uint4 w;
                w.x = pk2(f[2 * j].x, f[2 * j].y);
                w.y = pk2(f[2 * j].z, f[2 * j].w);
                w.z = pk2(f[2 * j + 1].x, f[2 * j + 1].y);
                w.w = pk2(f[2 * j + 1].z, f[2 * j + 1].w);
                int idx = (srow * 64 + shalf * 32 + j * 8) ^ ((srow & 7) << 3);
                *(uint4*)&Al[idx] = w;
            }
        }
        {
            const ushort* wp = &W1T[srow * 256 + k0 + shalf * 32];
#pragma unroll
            for (int j = 0; j < 4; j++) {
                uint4 w = *(const uint4*)&wp[j * 8];
                int idx = (srow * 64 + shalf * 32 + j * 8) ^ ((srow & 7) << 3);
                *(uint4*)&Bl[idx] = w;
            }
        }
        __syncthreads();
#pragma unroll
        for (int kk = 0; kk < 2; kk++) {
            bf16x8 a[4], b[4];
#pragma unroll
            for (int mi = 0; mi < 4; mi++) {
                int r = wr * 64 + mi * 16 + row16;
                a[mi] = *(const bf16x8*)&Al[(r * 64 + kk * 32 + kgrp * 8) ^ ((r & 7) << 3)];
            }
#pragma unroll
            for (int ni = 0; ni < 4; ni++) {
                int c = wc * 64 + ni * 16 + row16;
                b[ni] = *(const bf16x8*)&Bl[(c * 64 + kk * 32 + kgrp * 8) ^ ((c & 7) << 3)];
            }
#pragma unroll
            for (int mi = 0; mi < 4; mi++)
#pragma unroll
                for (int ni = 0; ni < 4; ni++)
                    acc[mi][ni] = __builtin_amdgcn_mfma_f32_16x16x32_bf16(
                        a[mi], b[ni], acc[mi][ni], 0, 0, 0);
        }
        __syncthreads();
    }
#pragma unroll
    for (int mi = 0; mi < 4; mi++) {
        int rbase = r0 + wr * 64 + mi * 16 + kgrp * 4;
#pragma unroll
        for (int ni = 0; ni < 4; ni++) {
            int col = wc * 64 + ni * 16 + row16;
#pragma unroll
            for (int r = 0; r < 4; r++) {
                int gr = rbase + r;
                if (gr < N) h1[(size_t)gr * 128 + col] = f2bf(acc[mi][ni][r]);
            }
        }
    }
}

// ---------------- Fused agg1 + bias + ReLU + GEMM2 (R6 structure, src-only CSR) ----------------
__global__ __launch_bounds__(256) void k_agg1(const ushort* __restrict__ h1,
                                              const float* __restrict__ dis,
                                              const int* __restrict__ off,
                                              const int* __restrict__ csr,
                                              const float* __restrict__ b1,
                                              const float* __restrict__ W2,
                                              ushort* __restrict__ h2, int N) {
    __shared__ float sh[4][128];
    int wave = threadIdx.x >> 6;
    int lane = threadIdx.x & 63;
    int node = blockIdx.x * 4 + wave;
    if (node >= N) return;

    int grp = lane >> 4, c = lane & 15;
    float w2r[32];
#pragma unroll
    for (int j = 0; j < 32; j++) w2r[j] = W2[(grp * 32 + j) * 16 + c];
    float2 bl = *(const float2*)&b1[lane * 2];

    float dd = dis[node];
    const uint* hp = (const uint*)h1;
    uint a = hp[(size_t)node * 64 + lane];
    float accx = bflo(a) * dd, accy = bfhi(a) * dd;  // self loop (x dd again below)

    int p0 = off[node], p1 = off[node + 1];
    for (int pb = p0; pb < p1; pb += 64) {
        int rem64 = p1 - pb;
        int cnt = rem64 < 64 ? rem64 : 64;
        int s = 0; float w = 0.f;
        if (lane < cnt) { s = csr[pb + lane]; w = dis[s]; }
        int j = 0;
        for (; j + 8 <= cnt; j += 8) {
            uint v[8]; float ww[8];
#pragma unroll
            for (int u = 0; u < 8; u++) {
                int ss = __shfl(s, j + u);
                ww[u] = __shfl(w, j + u);
                v[u] = hp[(size_t)ss * 64 + lane];
            }
#pragma unroll
            for (int u = 0; u < 8; u++) {
                accx += bflo(v[u]) * ww[u];
                accy += bfhi(v[u]) * ww[u];
            }
        }
        int rem = cnt - j;
        if (rem) {
            uint v[8]; float ww[8];
#pragma unroll
            for (int u = 0; u < 8; u++) {
                int ss = __shfl(s, j + u);
                float t = __shfl(w, j + u);
                ww[u] = (u < rem) ? t : 0.f;
                v[u] = (u < rem) ? hp[(size_t)ss * 64 + lane] : 0u;
            }
#pragma unroll
            for (int u = 0; u < 8; u++) {
                accx += bflo(v[u]) * ww[u];
                accy += bfhi(v[u]) * ww[u];
            }
        }
    }
    accx = fmaxf(accx * dd + bl.x, 0.f);
    accy = fmaxf(accy * dd + bl.y, 0.f);
    sh[wave][lane * 2]     = accx;
    sh[wave][lane * 2 + 1] = accy;
    float cs = 0.f;
#pragma unroll
    for (int j = 0; j < 32; j++) cs += sh[wave][grp * 32 + j] * w2r[j];
    cs += __shfl_xor(cs, 16);
    cs += __shfl_xor(cs, 32);
    if (lane < 16) h2[(size_t)node * 16 + lane] = f2bf(cs);
}

// ---------------- Aggregation layer 2 + b2 + log_softmax ----------------
__global__ __launch_bounds__(256) void k_final(const ushort* __restrict__ h2,
                                               const float* __restrict__ b2,
                                               const float* __restrict__ dis,
                                               const int* __restrict__ off,
                                               const int* __restrict__ csr,
                                               float* __restrict__ out, int N) {
    int g = threadIdx.x >> 2;
    int q = threadIdx.x & 3;
    int node = blockIdx.x * 64 + g;
    if (node >= N) return;
    float dd = dis[node];
    uint2 v0 = *(const uint2*)&h2[(size_t)node * 16 + q * 4];
    float a0 = bflo(v0.x) * dd, a1 = bfhi(v0.x) * dd;
    float a2 = bflo(v0.y) * dd, a3 = bfhi(v0.y) * dd;
    int p0 = off[node], p1 = off[node + 1];
    for (int pb = p0; pb < p1; pb += 4) {
        int rem4 = p1 - pb;
        int cnt = rem4 < 4 ? rem4 : 4;
        int s = 0; float w = 0.f;
        if (q < cnt) { s = csr[pb + q]; w = dis[s]; }
        uint2 vv[4]; float ww[4];
#pragma unroll
        for (int u = 0; u < 4; u++) {
            int ss = __shfl(s, u, 4);
            float t = __shfl(w, u, 4);
            ww[u] = (u < cnt) ? t : 0.f;
            if (u < cnt) vv[u] = *(const uint2*)&h2[(size_t)ss * 16 + q * 4];
            else         vv[u] = make_uint2(0u, 0u);
        }
#pragma unroll
        for (int u = 0; u < 4; u++) {
            a0 += bflo(vv[u].x) * ww[u]; a1 += bfhi(vv[u].x) * ww[u];
            a2 += bflo(vv[u].y) * ww[u]; a3 += bfhi(vv[u].y) * ww[u];
        }
    }
    a0 = a0 * dd + b2[q * 4 + 0];
    a1 = a1 * dd + b2[q * 4 + 1];
    a2 = a2 * dd + b2[q * 4 + 2];
    a3 = a3 * dd + b2[q * 4 + 3];
    float m = fmaxf(fmaxf(a0, a1), fmaxf(a2, a3));
    m = fmaxf(m, __shfl_xor(m, 1, 4));
    m = fmaxf(m, __shfl_xor(m, 2, 4));
    float s4 = expf(a0 - m) + expf(a1 - m) + expf(a2 - m) + expf(a3 - m);
    s4 += __shfl_xor(s4, 1, 4);
    s4 += __shfl_xor(s4, 2, 4);
    float l = m + logf(s4);
    f32x4 o = {a0 - l, a1 - l, a2 - l, a3 - l};
    *(f32x4*)&out[(size_t)node * 16 + q * 4] = o;
}

extern "C" void kernel_launch(void* const* d_in, const int* in_sizes, int n_in,
                              void* d_out, int out_size, void* d_ws, size_t ws_size,
                              hipStream_t stream) {
    const float* x    = (const float*)d_in[0];
    const int*   eidx = (const int*)d_in[1];
    const float* W1   = (const float*)d_in[2];
    const float* b1   = (const float*)d_in[3];
    const float* W2   = (const float*)d_in[4];
    const float* b2   = (const float*)d_in[5];
    float* out = (float*)d_out;

    int N = in_sizes[0] / IN_DIM;
    int E = in_sizes[1] / 2;
    const int* esrc = eidx;
    const int* edst = eidx + E;

    char* ws = (char*)d_ws;
    size_t wo = 0;
    auto alloc = [&](size_t bytes) -> void* {
        void* p = ws + wo;
        wo = (wo + bytes + 255) & ~(size_t)255;
        return p;
    };
    int NB = (N + 255) >> 8;   // 256-node buckets

    float*  dis     = (float*)alloc((size_t)N * 4);
    int*    offsets = (int*)alloc((size_t)(N + 1) * 4);
    int*    bcnt    = (int*)alloc(512 * 4);
    int*    bkbase  = (int*)alloc(512 * 4);
    int2*   part    = (int2*)alloc((size_t)NB * BK_CAP * 8);
    int*    csr     = (int*)alloc((size_t)E * 4);
    ushort* W1T     = (ushort*)alloc((size_t)IN_DIM * H_DIM * 2);
    ushort* h1      = (ushort*)alloc((size_t)N * H_DIM * 2);
    ushort* h2      = (ushort*)alloc((size_t)N * C_DIM * 2);

    k_zero  <<<2, 256, 0, stream>>>(bcnt, 512);
    k_part  <<<(E + CHUNK - 1) / CHUNK, 256, 0, stream>>>(esrc, edst, E, bcnt, part);
    k_bscan <<<1, 256, 0, stream>>>(bcnt, bkbase, offsets, N);
    k_bsort <<<NB, 256, 0, stream>>>(bcnt, bkbase, part, dis, offsets, csr, N);
    k_w1cast<<<H_DIM, IN_DIM, 0, stream>>>(W1, W1T);

    k_gemm1 <<<(N + 127) / 128, 256, 0, stream>>>(x, W1T, h1, N);
    k_agg1  <<<(N + 3) / 4, 256, 0, stream>>>(h1, dis, offsets, csr, b1, W2, h2, N);
    k_final <<<(N + 63) / 64, 256, 0, stream>>>(h2, b2, dis, offsets, csr, out, N);
}